// Round 1
// 1351.194 us; speedup vs baseline: 1.0708x; 1.0708x over previous
//
#include <hip/hip_runtime.h>
#include <hip/hip_bf16.h>

#define NE 8
#define TT 2048
#define HD 2048
#define ID 4096

typedef __attribute__((ext_vector_type(8))) short bf16x8;
typedef __attribute__((ext_vector_type(4))) float f32x4;
typedef __attribute__((ext_vector_type(4))) unsigned int u32x4;
typedef __attribute__((ext_vector_type(4))) unsigned short u16x4;
typedef __attribute__((ext_vector_type(8))) unsigned short u16x8;

__device__ __forceinline__ unsigned short f2bf(float f) {
  unsigned int u = __builtin_bit_cast(unsigned int, f);
  u += 0x7FFFu + ((u >> 16) & 1u);   // round-to-nearest-even
  return (unsigned short)(u >> 16);
}

__global__ void init_kernel(int* counts) {
  if (threadIdx.x < NE) counts[threadIdx.x] = 0;
}

// One block per token: logits(8), argmax, sigmoid, router_scores out,
// per-expert token list append, and bf16 copies of x and x*score.
__global__ __launch_bounds__(256) void router_kernel(
    const float* __restrict__ x, const float* __restrict__ rw,
    float* __restrict__ rs_out, unsigned short* __restrict__ xb,
    unsigned short* __restrict__ xsb, int* __restrict__ counts,
    int* __restrict__ tlist) {
  const int t = blockIdx.x;
  const int tid = threadIdx.x;
  const float* xr = x + (size_t)t * HD;
  float acc[NE];
#pragma unroll
  for (int e = 0; e < NE; ++e) acc[e] = 0.f;
  for (int h = tid; h < HD; h += 256) {
    float xv = xr[h];
#pragma unroll
    for (int e = 0; e < NE; ++e) acc[e] += xv * rw[e * HD + h];
  }
#pragma unroll
  for (int e = 0; e < NE; ++e) {
#pragma unroll
    for (int off = 32; off > 0; off >>= 1) acc[e] += __shfl_down(acc[e], off);
  }
  __shared__ float part[4][NE];
  __shared__ int sE;
  __shared__ float sS;
  const int wave = tid >> 6, lane = tid & 63;
  if (lane == 0) {
#pragma unroll
    for (int e = 0; e < NE; ++e) part[wave][e] = acc[e];
  }
  __syncthreads();
  if (tid == 0) {
    float best = -3.4e38f;
    int be = 0;
#pragma unroll
    for (int e = 0; e < NE; ++e) {
      float v = part[0][e] + part[1][e] + part[2][e] + part[3][e];
      if (v > best) { best = v; be = e; }   // strict > keeps lowest index
    }
    float s = 1.f / (1.f + expf(-best));
    sE = be;
    sS = s;
    int pos = atomicAdd(&counts[be], 1);
    tlist[be * TT + pos] = t;
  }
  __syncthreads();
  if (tid < NE) rs_out[tid * TT + t] = (tid == sE) ? sS : 0.f;
  const float s = sS;
  for (int h = tid; h < HD; h += 256) {
    float f = xr[h];
    xb[(size_t)t * HD + h] = f2bf(f);
    xsb[(size_t)t * HD + h] = f2bf(f * s);
  }
}

// Transpose-convert shared weights f32 [K][N] -> bf16 [N][K].
// z=0: shg (K=HD,N=ID) -> shgT[I][H]; z=1: shu same; z=2: shd (K=ID,N=HD) -> shdT[H][I].
__global__ __launch_bounds__(256) void tconv_kernel(
    const float* __restrict__ shg, const float* __restrict__ shu,
    const float* __restrict__ shd, unsigned short* __restrict__ shgT,
    unsigned short* __restrict__ shuT, unsigned short* __restrict__ shdT) {
  const int z = blockIdx.z;
  const float* src;
  unsigned short* dst;
  int K, N;
  if (z == 0)      { src = shg; dst = shgT; K = HD; N = ID; }
  else if (z == 1) { src = shu; dst = shuT; K = HD; N = ID; }
  else             { src = shd; dst = shdT; K = ID; N = HD; }
  const int kb = blockIdx.y * 64, nb = blockIdx.x * 64;
  if (kb >= K || nb >= N) return;
  __shared__ unsigned short tile[64][68];
  const int tid = threadIdx.x;
  const int rr = tid >> 4, cc = (tid & 15) * 4;
#pragma unroll
  for (int it = 0; it < 4; ++it) {
    int r = rr + it * 16;
    f32x4 v = *(const f32x4*)(const void*)(src + (size_t)(kb + r) * N + nb + cc);
    tile[r][cc + 0] = f2bf(v[0]);
    tile[r][cc + 1] = f2bf(v[1]);
    tile[r][cc + 2] = f2bf(v[2]);
    tile[r][cc + 3] = f2bf(v[3]);
  }
  __syncthreads();
  const int nr = tid >> 2, kc = (tid & 3) * 16;
#pragma unroll
  for (int h = 0; h < 2; ++h) {
    u16x8 w;
#pragma unroll
    for (int j = 0; j < 8; ++j) w[j] = tile[kc + h * 8 + j][nr];
    *(u16x8*)(void*)(dst + (size_t)(nb + nr) * K + kb + kc + h * 8) = w;
  }
}

// Grouped gate_up GEMM with reg-prefetch + double-buffered LDS pipeline.
// z=0..7: routed expert (A = xsb gathered rows, B = f32 gate_up_proj[e], fused cvt).
// z=8: shared MLP (A = xb identity rows; B = bf16 transposed shgT/shuT when shbf).
// Epilogue: h = silu(g)*u -> bf16 h buffer (row = token id).
__global__ __launch_bounds__(256) void gateup_kernel(
    const unsigned short* __restrict__ xb, const unsigned short* __restrict__ xsb,
    const float* __restrict__ gup, const float* __restrict__ shg,
    const float* __restrict__ shu, const unsigned short* __restrict__ shgT,
    const unsigned short* __restrict__ shuT, const int* __restrict__ counts,
    const int* __restrict__ tlist, unsigned short* __restrict__ hsh,
    unsigned short* __restrict__ hrt, const int shbf) {
  const int bz = blockIdx.z;
  const bool sh = (bz == NE);
  const int cnt = sh ? TT : counts[bz];
  const int row0 = blockIdx.y * 128;
  if (row0 >= cnt) return;
  const int n0 = blockIdx.x * 64;
  const unsigned short* Aptr = sh ? xb : xsb;
  const bool bfb = sh && (shbf != 0);
  const float *B1, *B2;
  size_t ldb;
  const unsigned short *T1 = nullptr, *T2 = nullptr;
  if (sh) {
    B1 = shg + n0; B2 = shu + n0; ldb = ID;
    T1 = shgT + (size_t)n0 * HD; T2 = shuT + (size_t)n0 * HD;
  } else {
    const float* base = gup + (size_t)bz * HD * 2 * ID;
    B1 = base + n0; B2 = base + ID + n0; ldb = 2 * ID;
  }
  unsigned short* hout = sh ? hsh : hrt;

  __shared__ int toks[128];
  __shared__ __align__(16) unsigned short As[2][128][40];  // stride 40 -> 80B rows, 16B-aligned frag reads
  __shared__ __align__(16) unsigned short Bg[2][64][40];
  __shared__ __align__(16) unsigned short Bu[2][64][40];

  const int tid = threadIdx.x;
  if (tid < 128) {
    int r = row0 + tid;
    toks[tid] = (r < cnt) ? (sh ? r : tlist[bz * TT + r]) : -1;
  }
  __syncthreads();

  const int lane = tid & 63, wave = tid >> 6;
  const int wm = (wave >> 1) * 64, wn = (wave & 1) * 32;
  const int rA0 = tid >> 2, cA = (tid & 3) * 8, rA1 = rA0 + 64;
  const int tok0 = toks[rA0], tok1 = toks[rA1];
  const unsigned short* ap0 = Aptr + ((tok0 >= 0) ? (size_t)tok0 * HD : 0) + cA;
  const unsigned short* ap1 = Aptr + ((tok1 >= 0) ? (size_t)tok1 * HD : 0) + cA;
  const int nB = tid & 63;
  const int kq0 = tid >> 6;  // 0..3
  const int fm = lane & 15, q = lane >> 4;
  const int nrT = tid >> 2, kcT = (tid & 3) * 8;

  const f32x4 zf = {0.f, 0.f, 0.f, 0.f};
  const u32x4 z4 = {0u, 0u, 0u, 0u};
  f32x4 accg[4][2], accu[4][2];
#pragma unroll
  for (int a = 0; a < 4; ++a)
#pragma unroll
    for (int b = 0; b < 2; ++b) { accg[a][b] = zf; accu[a][b] = zf; }

  // prefetch staging registers (loaded one K-step ahead of the LDS write)
  u32x4 ra0, ra1, tb1, tb2;
  f32x4 rg0, rg1, ru0, ru1;

#define GU_LOAD(K0)                                                            \
  do {                                                                         \
    ra0 = (tok0 >= 0) ? *(const u32x4*)(const void*)(ap0 + (K0)) : z4;         \
    ra1 = (tok1 >= 0) ? *(const u32x4*)(const void*)(ap1 + (K0)) : z4;         \
    if (bfb) {                                                                 \
      tb1 = *(const u32x4*)(const void*)(T1 + (size_t)nrT * HD + (K0) + kcT);  \
      tb2 = *(const u32x4*)(const void*)(T2 + (size_t)nrT * HD + (K0) + kcT);  \
    } else {                                                                   \
      const float* p1 = B1 + (size_t)((K0) + kq0 * 4) * ldb + nB;              \
      const float* p1b = p1 + 16 * ldb;                                        \
      rg0[0] = p1[0]; rg0[1] = p1[ldb]; rg0[2] = p1[2 * ldb]; rg0[3] = p1[3 * ldb]; \
      rg1[0] = p1b[0]; rg1[1] = p1b[ldb]; rg1[2] = p1b[2 * ldb]; rg1[3] = p1b[3 * ldb]; \
      const float* p2 = B2 + (size_t)((K0) + kq0 * 4) * ldb + nB;              \
      const float* p2b = p2 + 16 * ldb;                                        \
      ru0[0] = p2[0]; ru0[1] = p2[ldb]; ru0[2] = p2[2 * ldb]; ru0[3] = p2[3 * ldb]; \
      ru1[0] = p2b[0]; ru1[1] = p2b[ldb]; ru1[2] = p2b[2 * ldb]; ru1[3] = p2b[3 * ldb]; \
    }                                                                          \
  } while (0)

#define GU_WRITE(BUF)                                                          \
  do {                                                                         \
    *(u32x4*)(void*)&As[BUF][rA0][cA] = ra0;                                   \
    *(u32x4*)(void*)&As[BUF][rA1][cA] = ra1;                                   \
    if (bfb) {                                                                 \
      *(u32x4*)(void*)&Bg[BUF][nrT][kcT] = tb1;                                \
      *(u32x4*)(void*)&Bu[BUF][nrT][kcT] = tb2;                                \
    } else {                                                                   \
      u16x4 w;                                                                 \
      w[0] = f2bf(rg0[0]); w[1] = f2bf(rg0[1]); w[2] = f2bf(rg0[2]); w[3] = f2bf(rg0[3]); \
      *(u16x4*)(void*)&Bg[BUF][nB][kq0 * 4] = w;                               \
      w[0] = f2bf(rg1[0]); w[1] = f2bf(rg1[1]); w[2] = f2bf(rg1[2]); w[3] = f2bf(rg1[3]); \
      *(u16x4*)(void*)&Bg[BUF][nB][kq0 * 4 + 16] = w;                          \
      w[0] = f2bf(ru0[0]); w[1] = f2bf(ru0[1]); w[2] = f2bf(ru0[2]); w[3] = f2bf(ru0[3]); \
      *(u16x4*)(void*)&Bu[BUF][nB][kq0 * 4] = w;                               \
      w[0] = f2bf(ru1[0]); w[1] = f2bf(ru1[1]); w[2] = f2bf(ru1[2]); w[3] = f2bf(ru1[3]); \
      *(u16x4*)(void*)&Bu[BUF][nB][kq0 * 4 + 16] = w;                          \
    }                                                                          \
  } while (0)

  GU_LOAD(0);
  GU_WRITE(0);
  GU_LOAD(32);
  asm volatile("s_waitcnt lgkmcnt(0)" ::: "memory");
  __builtin_amdgcn_sched_barrier(0);
  __builtin_amdgcn_s_barrier();

  for (int t = 0; t < HD / 32; ++t) {
    const int cur = t & 1;
    bf16x8 af[4], bgf[2], buf2[2];
#pragma unroll
    for (int mt = 0; mt < 4; ++mt)
      af[mt] = __builtin_bit_cast(bf16x8,
               *(const u32x4*)(const void*)&As[cur][wm + mt * 16 + fm][q * 8]);
#pragma unroll
    for (int nt = 0; nt < 2; ++nt) {
      bgf[nt] = __builtin_bit_cast(bf16x8,
                *(const u32x4*)(const void*)&Bg[cur][wn + nt * 16 + fm][q * 8]);
      buf2[nt] = __builtin_bit_cast(bf16x8,
                 *(const u32x4*)(const void*)&Bu[cur][wn + nt * 16 + fm][q * 8]);
    }
    if (t + 1 < HD / 32) GU_WRITE(cur ^ 1);     // auto counted-vmcnt wait on regs
    if (t + 2 < HD / 32) GU_LOAD((t + 2) * 32); // next prefetch in flight across barrier
    __builtin_amdgcn_s_setprio(1);
#pragma unroll
    for (int mt = 0; mt < 4; ++mt)
#pragma unroll
      for (int nt = 0; nt < 2; ++nt) {
        accg[mt][nt] = __builtin_amdgcn_mfma_f32_16x16x32_bf16(af[mt], bgf[nt], accg[mt][nt], 0, 0, 0);
        accu[mt][nt] = __builtin_amdgcn_mfma_f32_16x16x32_bf16(af[mt], buf2[nt], accu[mt][nt], 0, 0, 0);
      }
    __builtin_amdgcn_s_setprio(0);
    asm volatile("s_waitcnt lgkmcnt(0)" ::: "memory");
    __builtin_amdgcn_sched_barrier(0);
    __builtin_amdgcn_s_barrier();
  }
#undef GU_LOAD
#undef GU_WRITE

  // ---- epilogue: silu(g)*u ----
#pragma unroll
  for (int mt = 0; mt < 4; ++mt)
#pragma unroll
    for (int nt = 0; nt < 2; ++nt)
#pragma unroll
      for (int r = 0; r < 4; ++r) {
        int ml = wm + mt * 16 + q * 4 + r;
        if (row0 + ml < cnt) {
          int tok = toks[ml];
          int n = n0 + wn + nt * 16 + fm;
          float g = accg[mt][nt][r], u = accu[mt][nt][r];
          float hv = g / (1.f + __expf(-g)) * u;
          hout[(size_t)tok * ID + n] = f2bf(hv);
        }
      }
}

// Down-proj GEMM, same pipeline. routed==0: A = hsh identity rows, dense write
// (bf16 shdT path when shbf). routed==1: z = expert, A = hrt gathered rows, +=.
__global__ __launch_bounds__(256) void down_kernel(
    const unsigned short* __restrict__ Ah, const float* __restrict__ Bbase,
    const unsigned short* __restrict__ BT, const int* __restrict__ counts,
    const int* __restrict__ tlist, float* __restrict__ out,
    const int routed, const int shbf) {
  const int e = blockIdx.z;
  const int cnt = routed ? counts[e] : TT;
  const int row0 = blockIdx.y * 128;
  if (row0 >= cnt) return;
  const int n0 = blockIdx.x * 64;
  const bool bfb = (!routed) && (shbf != 0);
  const float* B = routed ? (Bbase + (size_t)e * ID * HD + n0) : (Bbase + n0);
  const unsigned short* T = BT + (size_t)n0 * ID;

  __shared__ int toks[128];
  __shared__ __align__(16) unsigned short As[2][128][40];
  __shared__ __align__(16) unsigned short Bs[2][64][40];

  const int tid = threadIdx.x;
  if (tid < 128) {
    int r = row0 + tid;
    toks[tid] = (r < cnt) ? (routed ? tlist[e * TT + r] : r) : -1;
  }
  __syncthreads();

  const int lane = tid & 63, wave = tid >> 6;
  const int wm = (wave >> 1) * 64, wn = (wave & 1) * 32;
  const int rA0 = tid >> 2, cA = (tid & 3) * 8, rA1 = rA0 + 64;
  const int tok0 = toks[rA0], tok1 = toks[rA1];
  const unsigned short* ap0 = Ah + ((tok0 >= 0) ? (size_t)tok0 * ID : 0) + cA;
  const unsigned short* ap1 = Ah + ((tok1 >= 0) ? (size_t)tok1 * ID : 0) + cA;
  const int nB = tid & 63;
  const int kq0 = tid >> 6;
  const int fm = lane & 15, q = lane >> 4;
  const int nrT = tid >> 2, kcT = (tid & 3) * 8;

  const f32x4 zf = {0.f, 0.f, 0.f, 0.f};
  const u32x4 z4 = {0u, 0u, 0u, 0u};
  f32x4 acc[4][2];
#pragma unroll
  for (int a = 0; a < 4; ++a)
#pragma unroll
    for (int b = 0; b < 2; ++b) acc[a][b] = zf;

  u32x4 ra0, ra1, tb;
  f32x4 rb0, rb1;

#define DN_LOAD(K0)                                                            \
  do {                                                                         \
    ra0 = (tok0 >= 0) ? *(const u32x4*)(const void*)(ap0 + (K0)) : z4;         \
    ra1 = (tok1 >= 0) ? *(const u32x4*)(const void*)(ap1 + (K0)) : z4;         \
    if (bfb) {                                                                 \
      tb = *(const u32x4*)(const void*)(T + (size_t)nrT * ID + (K0) + kcT);    \
    } else {                                                                   \
      const float* p = B + (size_t)((K0) + kq0 * 4) * HD + nB;                 \
      const float* pb = p + 16 * HD;                                           \
      rb0[0] = p[0]; rb0[1] = p[HD]; rb0[2] = p[2 * HD]; rb0[3] = p[3 * HD];   \
      rb1[0] = pb[0]; rb1[1] = pb[HD]; rb1[2] = pb[2 * HD]; rb1[3] = pb[3 * HD]; \
    }                                                                          \
  } while (0)

#define DN_WRITE(BUF)                                                          \
  do {                                                                         \
    *(u32x4*)(void*)&As[BUF][rA0][cA] = ra0;                                   \
    *(u32x4*)(void*)&As[BUF][rA1][cA] = ra1;                                   \
    if (bfb) {                                                                 \
      *(u32x4*)(void*)&Bs[BUF][nrT][kcT] = tb;                                 \
    } else {                                                                   \
      u16x4 w;                                                                 \
      w[0] = f2bf(rb0[0]); w[1] = f2bf(rb0[1]); w[2] = f2bf(rb0[2]); w[3] = f2bf(rb0[3]); \
      *(u16x4*)(void*)&Bs[BUF][nB][kq0 * 4] = w;                               \
      w[0] = f2bf(rb1[0]); w[1] = f2bf(rb1[1]); w[2] = f2bf(rb1[2]); w[3] = f2bf(rb1[3]); \
      *(u16x4*)(void*)&Bs[BUF][nB][kq0 * 4 + 16] = w;                          \
    }                                                                          \
  } while (0)

  DN_LOAD(0);
  DN_WRITE(0);
  DN_LOAD(32);
  asm volatile("s_waitcnt lgkmcnt(0)" ::: "memory");
  __builtin_amdgcn_sched_barrier(0);
  __builtin_amdgcn_s_barrier();

  for (int t = 0; t < ID / 32; ++t) {
    const int cur = t & 1;
    bf16x8 af[4], bfr[2];
#pragma unroll
    for (int mt = 0; mt < 4; ++mt)
      af[mt] = __builtin_bit_cast(bf16x8,
               *(const u32x4*)(const void*)&As[cur][wm + mt * 16 + fm][q * 8]);
#pragma unroll
    for (int nt = 0; nt < 2; ++nt)
      bfr[nt] = __builtin_bit_cast(bf16x8,
                *(const u32x4*)(const void*)&Bs[cur][wn + nt * 16 + fm][q * 8]);
    if (t + 1 < ID / 32) DN_WRITE(cur ^ 1);
    if (t + 2 < ID / 32) DN_LOAD((t + 2) * 32);
    __builtin_amdgcn_s_setprio(1);
#pragma unroll
    for (int mt = 0; mt < 4; ++mt)
#pragma unroll
      for (int nt = 0; nt < 2; ++nt)
        acc[mt][nt] = __builtin_amdgcn_mfma_f32_16x16x32_bf16(af[mt], bfr[nt], acc[mt][nt], 0, 0, 0);
    __builtin_amdgcn_s_setprio(0);
    asm volatile("s_waitcnt lgkmcnt(0)" ::: "memory");
    __builtin_amdgcn_sched_barrier(0);
    __builtin_amdgcn_s_barrier();
  }
#undef DN_LOAD
#undef DN_WRITE

#pragma unroll
  for (int mt = 0; mt < 4; ++mt)
#pragma unroll
    for (int nt = 0; nt < 2; ++nt)
#pragma unroll
      for (int r = 0; r < 4; ++r) {
        int ml = wm + mt * 16 + q * 4 + r;
        if (row0 + ml < cnt) {
          int tok = toks[ml];
          int n = n0 + wn + nt * 16 + fm;
          float v = acc[mt][nt][r];
          float* o = out + (size_t)tok * HD + n;
          if (routed) *o += v; else *o = v;
        }
      }
}

extern "C" void kernel_launch(void* const* d_in, const int* in_sizes, int n_in,
                              void* d_out, int out_size, void* d_ws, size_t ws_size,
                              hipStream_t stream) {
  const float* x   = (const float*)d_in[0];
  const float* rw  = (const float*)d_in[1];
  const float* gup = (const float*)d_in[2];
  const float* dwn = (const float*)d_in[3];
  const float* shg = (const float*)d_in[4];
  const float* shu = (const float*)d_in[5];
  const float* shd = (const float*)d_in[6];
  float* out = (float*)d_out;

  char* ws = (char*)d_ws;
  int* counts = (int*)ws;                                    // 32 B
  int* tlist = (int*)(ws + 1024);                            // 64 KB
  unsigned short* xb  = (unsigned short*)(ws + (1 << 17));               // 8 MB
  unsigned short* xsb = (unsigned short*)(ws + (1 << 17) + 8388608);     // 8 MB
  unsigned short* hsh = (unsigned short*)(ws + (1 << 17) + 16777216);    // 16 MB
  unsigned short* hrt = (unsigned short*)(ws + (1 << 17) + 33554432);    // 16 MB
  const size_t WB = (size_t)(1 << 17) + 50331648;            // 50,462,720
  unsigned short* shgT = (unsigned short*)(ws + WB);                     // 16 MB
  unsigned short* shuT = (unsigned short*)(ws + WB + 16777216);          // 16 MB
  unsigned short* shdT = (unsigned short*)(ws + WB + 33554432);          // 16 MB
  const size_t need = WB + 3ull * 16777216ull;               // ~96.1 MB
  const int shbf = (ws_size >= need) ? 1 : 0;

  hipLaunchKernelGGL(init_kernel, dim3(1), dim3(64), 0, stream, counts);
  hipLaunchKernelGGL(router_kernel, dim3(TT), dim3(256), 0, stream,
                     x, rw, out + (size_t)TT * HD, xb, xsb, counts, tlist);
  if (shbf)
    hipLaunchKernelGGL(tconv_kernel, dim3(64, 64, 3), dim3(256), 0, stream,
                       shg, shu, shd, shgT, shuT, shdT);
  hipLaunchKernelGGL(gateup_kernel, dim3(ID / 64, TT / 128, NE + 1), dim3(256), 0, stream,
                     xb, xsb, gup, shg, shu, shgT, shuT, counts, tlist, hsh, hrt, shbf);
  hipLaunchKernelGGL(down_kernel, dim3(HD / 64, TT / 128, 1), dim3(256), 0, stream,
                     hsh, shd, shdT, counts, tlist, out, 0, shbf);
  hipLaunchKernelGGL(down_kernel, dim3(HD / 64, TT / 128, NE), dim3(256), 0, stream,
                     hrt, dwn, shdT, counts, tlist, out, 1, shbf);
}

// Round 3
// 1312.861 us; speedup vs baseline: 1.1020x; 1.0292x over previous
//
#include <hip/hip_runtime.h>
#include <hip/hip_bf16.h>

#define NE 8
#define TT 2048
#define HD 2048
#define ID 4096

typedef __attribute__((ext_vector_type(8))) short bf16x8;
typedef __attribute__((ext_vector_type(4))) float f32x4;
typedef __attribute__((ext_vector_type(4))) unsigned int u32x4;
typedef __attribute__((ext_vector_type(2))) unsigned int u32x2;
typedef __attribute__((ext_vector_type(4))) unsigned short u16x4;
typedef __attribute__((ext_vector_type(8))) unsigned short u16x8;

// native scalar cast -> compiler emits packed v_cvt_pk_bf16_f32 (RNE)
__device__ __forceinline__ unsigned short f2bf(float f) {
  return __builtin_bit_cast(unsigned short, __float2bfloat16(f));
}

__global__ void init_kernel(int* counts) {
  if (threadIdx.x < NE) counts[threadIdx.x] = 0;
}

// One block per token: logits(8), argmax, sigmoid, router_scores out,
// per-expert token list append, and bf16 copies of x and x*score.
__global__ __launch_bounds__(256) void router_kernel(
    const float* __restrict__ x, const float* __restrict__ rw,
    float* __restrict__ rs_out, unsigned short* __restrict__ xb,
    unsigned short* __restrict__ xsb, int* __restrict__ counts,
    int* __restrict__ tlist) {
  const int t = blockIdx.x;
  const int tid = threadIdx.x;
  const float* xr = x + (size_t)t * HD;
  float acc[NE];
#pragma unroll
  for (int e = 0; e < NE; ++e) acc[e] = 0.f;
  for (int h = tid; h < HD; h += 256) {
    float xv = xr[h];
#pragma unroll
    for (int e = 0; e < NE; ++e) acc[e] += xv * rw[e * HD + h];
  }
#pragma unroll
  for (int e = 0; e < NE; ++e) {
#pragma unroll
    for (int off = 32; off > 0; off >>= 1) acc[e] += __shfl_down(acc[e], off);
  }
  __shared__ float part[4][NE];
  __shared__ int sE;
  __shared__ float sS;
  const int wave = tid >> 6, lane = tid & 63;
  if (lane == 0) {
#pragma unroll
    for (int e = 0; e < NE; ++e) part[wave][e] = acc[e];
  }
  __syncthreads();
  if (tid == 0) {
    float best = -3.4e38f;
    int be = 0;
#pragma unroll
    for (int e = 0; e < NE; ++e) {
      float v = part[0][e] + part[1][e] + part[2][e] + part[3][e];
      if (v > best) { best = v; be = e; }   // strict > keeps lowest index
    }
    float s = 1.f / (1.f + expf(-best));
    sE = be;
    sS = s;
    int pos = atomicAdd(&counts[be], 1);
    tlist[be * TT + pos] = t;
  }
  __syncthreads();
  if (tid < NE) rs_out[tid * TT + t] = (tid == sE) ? sS : 0.f;
  const float s = sS;
  for (int h = tid; h < HD; h += 256) {
    float f = xr[h];
    xb[(size_t)t * HD + h] = f2bf(f);
    xsb[(size_t)t * HD + h] = f2bf(f * s);
  }
}

// Transpose-convert shared weights f32 [K][N] -> bf16 [N][K].
__global__ __launch_bounds__(256) void tconv_kernel(
    const float* __restrict__ shg, const float* __restrict__ shu,
    const float* __restrict__ shd, unsigned short* __restrict__ shgT,
    unsigned short* __restrict__ shuT, unsigned short* __restrict__ shdT) {
  const int z = blockIdx.z;
  const float* src;
  unsigned short* dst;
  int K, N;
  if (z == 0)      { src = shg; dst = shgT; K = HD; N = ID; }
  else if (z == 1) { src = shu; dst = shuT; K = HD; N = ID; }
  else             { src = shd; dst = shdT; K = ID; N = HD; }
  const int kb = blockIdx.y * 64, nb = blockIdx.x * 64;
  if (kb >= K || nb >= N) return;
  __shared__ unsigned short tile[64][68];
  const int tid = threadIdx.x;
  const int rr = tid >> 4, cc = (tid & 15) * 4;
#pragma unroll
  for (int it = 0; it < 4; ++it) {
    int r = rr + it * 16;
    f32x4 v = *(const f32x4*)(const void*)(src + (size_t)(kb + r) * N + nb + cc);
    tile[r][cc + 0] = f2bf(v[0]);
    tile[r][cc + 1] = f2bf(v[1]);
    tile[r][cc + 2] = f2bf(v[2]);
    tile[r][cc + 3] = f2bf(v[3]);
  }
  __syncthreads();
  const int nr = tid >> 2, kc = (tid & 3) * 16;
#pragma unroll
  for (int h = 0; h < 2; ++h) {
    u16x8 w;
#pragma unroll
    for (int j = 0; j < 8; ++j) w[j] = tile[kc + h * 8 + j][nr];
    *(u16x8*)(void*)(dst + (size_t)(nb + nr) * K + kb + kc + h * 8) = w;
  }
}

// ---------------- gate_up: routed experts (fused f32->bf16 B staging) --------
__global__ __launch_bounds__(256) void gu_routed_kernel(
    const unsigned short* __restrict__ xsb, const float* __restrict__ gup,
    const int* __restrict__ counts, const int* __restrict__ tlist,
    unsigned short* __restrict__ hrt) {
  const int e = blockIdx.z;
  const int cnt = counts[e];
  const int row0 = blockIdx.y * 128;
  if (row0 >= cnt) return;
  const int n0 = blockIdx.x * 64;
  const float* Bb = gup + (size_t)e * HD * (2 * ID);
  const float* B1 = Bb + n0;
  const float* B2 = Bb + ID + n0;
  const size_t ldb = 2 * ID;

  __shared__ int toks[128];
  __shared__ __align__(16) unsigned short As[2][128][40];
  __shared__ __align__(16) unsigned short Bg[2][64][36];
  __shared__ __align__(16) unsigned short Bu[2][64][36];

  const int tid = threadIdx.x;
  if (tid < 128) {
    int r = row0 + tid;
    toks[tid] = (r < cnt) ? tlist[e * TT + r] : -1;
  }
  __syncthreads();

  const int lane = tid & 63, wave = tid >> 6;
  const int wm = (wave >> 1) * 64, wn = (wave & 1) * 32;
  const int rA0 = tid >> 2, cA = (tid & 3) * 8, rA1 = rA0 + 64;
  const int tok0 = toks[rA0], tok1 = toks[rA1];
  const unsigned short* ap0 = xsb + ((tok0 >= 0) ? (size_t)tok0 * HD : 0) + cA;
  const unsigned short* ap1 = xsb + ((tok1 >= 0) ? (size_t)tok1 * HD : 0) + cA;
  const int nB = tid & 63;
  const int kq0 = tid >> 6;
  const int fm = lane & 15, q = lane >> 4;

  const f32x4 zf = {0.f, 0.f, 0.f, 0.f};
  const u32x4 z4 = {0u, 0u, 0u, 0u};
  f32x4 accg[4][2], accu[4][2];
#pragma unroll
  for (int a = 0; a < 4; ++a)
#pragma unroll
    for (int b = 0; b < 2; ++b) { accg[a][b] = zf; accu[a][b] = zf; }

  u32x4 ra0, ra1;
  f32x4 rg0, rg1, ru0, ru1;

#define LD(K0)                                                                 \
  do {                                                                         \
    ra0 = (tok0 >= 0) ? *(const u32x4*)(const void*)(ap0 + (K0)) : z4;         \
    ra1 = (tok1 >= 0) ? *(const u32x4*)(const void*)(ap1 + (K0)) : z4;         \
    const float* p1 = B1 + (size_t)((K0) + kq0 * 4) * ldb + nB;                \
    const float* p1b = p1 + 16 * ldb;                                          \
    rg0[0] = p1[0]; rg0[1] = p1[ldb]; rg0[2] = p1[2 * ldb]; rg0[3] = p1[3 * ldb]; \
    rg1[0] = p1b[0]; rg1[1] = p1b[ldb]; rg1[2] = p1b[2 * ldb]; rg1[3] = p1b[3 * ldb]; \
    const float* p2 = B2 + (size_t)((K0) + kq0 * 4) * ldb + nB;                \
    const float* p2b = p2 + 16 * ldb;                                          \
    ru0[0] = p2[0]; ru0[1] = p2[ldb]; ru0[2] = p2[2 * ldb]; ru0[3] = p2[3 * ldb]; \
    ru1[0] = p2b[0]; ru1[1] = p2b[ldb]; ru1[2] = p2b[2 * ldb]; ru1[3] = p2b[3 * ldb]; \
  } while (0)

#define WR(BUF)                                                                \
  do {                                                                         \
    *(u32x4*)(void*)&As[BUF][rA0][cA] = ra0;                                   \
    *(u32x4*)(void*)&As[BUF][rA1][cA] = ra1;                                   \
    u16x4 w;                                                                   \
    w[0] = f2bf(rg0[0]); w[1] = f2bf(rg0[1]); w[2] = f2bf(rg0[2]); w[3] = f2bf(rg0[3]); \
    *(u16x4*)(void*)&Bg[BUF][nB][kq0 * 4] = w;                                 \
    w[0] = f2bf(rg1[0]); w[1] = f2bf(rg1[1]); w[2] = f2bf(rg1[2]); w[3] = f2bf(rg1[3]); \
    *(u16x4*)(void*)&Bg[BUF][nB][kq0 * 4 + 16] = w;                            \
    w[0] = f2bf(ru0[0]); w[1] = f2bf(ru0[1]); w[2] = f2bf(ru0[2]); w[3] = f2bf(ru0[3]); \
    *(u16x4*)(void*)&Bu[BUF][nB][kq0 * 4] = w;                                 \
    w[0] = f2bf(ru1[0]); w[1] = f2bf(ru1[1]); w[2] = f2bf(ru1[2]); w[3] = f2bf(ru1[3]); \
    *(u16x4*)(void*)&Bu[BUF][nB][kq0 * 4 + 16] = w;                            \
  } while (0)

  LD(0);
  WR(0);
  LD(32);
  asm volatile("s_waitcnt lgkmcnt(0)" ::: "memory");
  __builtin_amdgcn_sched_barrier(0);
  __builtin_amdgcn_s_barrier();

  constexpr int NT = HD / 32;
  for (int t = 0; t < NT; ++t) {
    const int cur = t & 1;
    bf16x8 af[4], bgf[2], bud[2];
#pragma unroll
    for (int mt = 0; mt < 4; ++mt)
      af[mt] = __builtin_bit_cast(bf16x8,
               *(const u32x4*)(const void*)&As[cur][wm + mt * 16 + fm][q * 8]);
#pragma unroll
    for (int nt = 0; nt < 2; ++nt) {
      const unsigned short* bp = &Bg[cur][wn + nt * 16 + fm][q * 8];
      u32x2 lo = *(const u32x2*)(const void*)bp;
      u32x2 hi = *(const u32x2*)(const void*)(bp + 4);
      u32x4 v; v[0] = lo[0]; v[1] = lo[1]; v[2] = hi[0]; v[3] = hi[1];
      bgf[nt] = __builtin_bit_cast(bf16x8, v);
      const unsigned short* bp2 = &Bu[cur][wn + nt * 16 + fm][q * 8];
      lo = *(const u32x2*)(const void*)bp2;
      hi = *(const u32x2*)(const void*)(bp2 + 4);
      v[0] = lo[0]; v[1] = lo[1]; v[2] = hi[0]; v[3] = hi[1];
      bud[nt] = __builtin_bit_cast(bf16x8, v);
    }
    __builtin_amdgcn_s_setprio(1);
#pragma unroll
    for (int mt = 0; mt < 4; ++mt)
#pragma unroll
      for (int nt = 0; nt < 2; ++nt) {
        accg[mt][nt] = __builtin_amdgcn_mfma_f32_16x16x32_bf16(af[mt], bgf[nt], accg[mt][nt], 0, 0, 0);
        accu[mt][nt] = __builtin_amdgcn_mfma_f32_16x16x32_bf16(af[mt], bud[nt], accu[mt][nt], 0, 0, 0);
      }
    __builtin_amdgcn_s_setprio(0);
    __builtin_amdgcn_sched_barrier(0);  // keep WR's cvt+vmcnt wait below the MFMAs
    if (t + 1 < NT) WR(cur ^ 1);        // consumes K=(t+1) regs (loaded at t-1)
    if (t + 2 < NT) LD((t + 2) * 32);   // refill regs; in flight across barrier
    asm volatile("s_waitcnt lgkmcnt(0)" ::: "memory");
    __builtin_amdgcn_sched_barrier(0);
    __builtin_amdgcn_s_barrier();
  }
#undef LD
#undef WR

#pragma unroll
  for (int mt = 0; mt < 4; ++mt)
#pragma unroll
    for (int nt = 0; nt < 2; ++nt)
#pragma unroll
      for (int r = 0; r < 4; ++r) {
        int ml = wm + mt * 16 + q * 4 + r;
        if (row0 + ml < cnt) {
          int tok = toks[ml];
          int n = n0 + wn + nt * 16 + fm;
          float g = accg[mt][nt][r], u = accu[mt][nt][r];
          float hv = g / (1.f + __expf(-g)) * u;
          hrt[(size_t)tok * ID + n] = f2bf(hv);
        }
      }
}

// ---------------- gate_up: shared MLP (BF=1: pre-converted bf16 B) -----------
template <int BF>
__global__ __launch_bounds__(256) void gu_shared_kernel(
    const unsigned short* __restrict__ xb, const float* __restrict__ shg,
    const float* __restrict__ shu, const unsigned short* __restrict__ shgT,
    const unsigned short* __restrict__ shuT, unsigned short* __restrict__ hsh) {
  const int row0 = blockIdx.y * 128;
  const int n0 = blockIdx.x * 64;
  const float* B1 = shg + n0;
  const float* B2 = shu + n0;
  const size_t ldb = ID;
  const unsigned short* T1 = shgT + (size_t)n0 * HD;
  const unsigned short* T2 = shuT + (size_t)n0 * HD;

  __shared__ __align__(16) unsigned short As[2][128][40];
  __shared__ __align__(16) unsigned short Bg[2][64][36];
  __shared__ __align__(16) unsigned short Bu[2][64][36];

  const int tid = threadIdx.x;
  const int lane = tid & 63, wave = tid >> 6;
  const int wm = (wave >> 1) * 64, wn = (wave & 1) * 32;
  const int rA0 = tid >> 2, cA = (tid & 3) * 8, rA1 = rA0 + 64;
  const unsigned short* ap0 = xb + (size_t)(row0 + rA0) * HD + cA;
  const unsigned short* ap1 = xb + (size_t)(row0 + rA1) * HD + cA;
  const int nB = tid & 63;
  const int kq0 = tid >> 6;
  const int fm = lane & 15, q = lane >> 4;
  const int nrT = tid >> 2, kcT = (tid & 3) * 8;

  const f32x4 zf = {0.f, 0.f, 0.f, 0.f};
  f32x4 accg[4][2], accu[4][2];
#pragma unroll
  for (int a = 0; a < 4; ++a)
#pragma unroll
    for (int b = 0; b < 2; ++b) { accg[a][b] = zf; accu[a][b] = zf; }

  u32x4 ra0, ra1, tb1, tb2;
  f32x4 rg0, rg1, ru0, ru1;

#define LD(K0)                                                                 \
  do {                                                                         \
    ra0 = *(const u32x4*)(const void*)(ap0 + (K0));                            \
    ra1 = *(const u32x4*)(const void*)(ap1 + (K0));                            \
    if constexpr (BF) {                                                        \
      tb1 = *(const u32x4*)(const void*)(T1 + (size_t)nrT * HD + (K0) + kcT);  \
      tb2 = *(const u32x4*)(const void*)(T2 + (size_t)nrT * HD + (K0) + kcT);  \
    } else {                                                                   \
      const float* p1 = B1 + (size_t)((K0) + kq0 * 4) * ldb + nB;              \
      const float* p1b = p1 + 16 * ldb;                                        \
      rg0[0] = p1[0]; rg0[1] = p1[ldb]; rg0[2] = p1[2 * ldb]; rg0[3] = p1[3 * ldb]; \
      rg1[0] = p1b[0]; rg1[1] = p1b[ldb]; rg1[2] = p1b[2 * ldb]; rg1[3] = p1b[3 * ldb]; \
      const float* p2 = B2 + (size_t)((K0) + kq0 * 4) * ldb + nB;              \
      const float* p2b = p2 + 16 * ldb;                                        \
      ru0[0] = p2[0]; ru0[1] = p2[ldb]; ru0[2] = p2[2 * ldb]; ru0[3] = p2[3 * ldb]; \
      ru1[0] = p2b[0]; ru1[1] = p2b[ldb]; ru1[2] = p2b[2 * ldb]; ru1[3] = p2b[3 * ldb]; \
    }                                                                          \
  } while (0)

#define WR(BUF)                                                                \
  do {                                                                         \
    *(u32x4*)(void*)&As[BUF][rA0][cA] = ra0;                                   \
    *(u32x4*)(void*)&As[BUF][rA1][cA] = ra1;                                   \
    if constexpr (BF) {                                                        \
      u32x2 lo, hi;                                                            \
      lo[0] = tb1[0]; lo[1] = tb1[1]; hi[0] = tb1[2]; hi[1] = tb1[3];          \
      *(u32x2*)(void*)&Bg[BUF][nrT][kcT] = lo;                                 \
      *(u32x2*)(void*)&Bg[BUF][nrT][kcT + 4] = hi;                             \
      lo[0] = tb2[0]; lo[1] = tb2[1]; hi[0] = tb2[2]; hi[1] = tb2[3];          \
      *(u32x2*)(void*)&Bu[BUF][nrT][kcT] = lo;                                 \
      *(u32x2*)(void*)&Bu[BUF][nrT][kcT + 4] = hi;                             \
    } else {                                                                   \
      u16x4 w;                                                                 \
      w[0] = f2bf(rg0[0]); w[1] = f2bf(rg0[1]); w[2] = f2bf(rg0[2]); w[3] = f2bf(rg0[3]); \
      *(u16x4*)(void*)&Bg[BUF][nB][kq0 * 4] = w;                               \
      w[0] = f2bf(rg1[0]); w[1] = f2bf(rg1[1]); w[2] = f2bf(rg1[2]); w[3] = f2bf(rg1[3]); \
      *(u16x4*)(void*)&Bg[BUF][nB][kq0 * 4 + 16] = w;                          \
      w[0] = f2bf(ru0[0]); w[1] = f2bf(ru0[1]); w[2] = f2bf(ru0[2]); w[3] = f2bf(ru0[3]); \
      *(u16x4*)(void*)&Bu[BUF][nB][kq0 * 4] = w;                               \
      w[0] = f2bf(ru1[0]); w[1] = f2bf(ru1[1]); w[2] = f2bf(ru1[2]); w[3] = f2bf(ru1[3]); \
      *(u16x4*)(void*)&Bu[BUF][nB][kq0 * 4 + 16] = w;                          \
    }                                                                          \
  } while (0)

  LD(0);
  WR(0);
  LD(32);
  asm volatile("s_waitcnt lgkmcnt(0)" ::: "memory");
  __builtin_amdgcn_sched_barrier(0);
  __builtin_amdgcn_s_barrier();

  constexpr int NT = HD / 32;
  for (int t = 0; t < NT; ++t) {
    const int cur = t & 1;
    bf16x8 af[4], bgf[2], bud[2];
#pragma unroll
    for (int mt = 0; mt < 4; ++mt)
      af[mt] = __builtin_bit_cast(bf16x8,
               *(const u32x4*)(const void*)&As[cur][wm + mt * 16 + fm][q * 8]);
#pragma unroll
    for (int nt = 0; nt < 2; ++nt) {
      const unsigned short* bp = &Bg[cur][wn + nt * 16 + fm][q * 8];
      u32x2 lo = *(const u32x2*)(const void*)bp;
      u32x2 hi = *(const u32x2*)(const void*)(bp + 4);
      u32x4 v; v[0] = lo[0]; v[1] = lo[1]; v[2] = hi[0]; v[3] = hi[1];
      bgf[nt] = __builtin_bit_cast(bf16x8, v);
      const unsigned short* bp2 = &Bu[cur][wn + nt * 16 + fm][q * 8];
      lo = *(const u32x2*)(const void*)bp2;
      hi = *(const u32x2*)(const void*)(bp2 + 4);
      v[0] = lo[0]; v[1] = lo[1]; v[2] = hi[0]; v[3] = hi[1];
      bud[nt] = __builtin_bit_cast(bf16x8, v);
    }
    __builtin_amdgcn_s_setprio(1);
#pragma unroll
    for (int mt = 0; mt < 4; ++mt)
#pragma unroll
      for (int nt = 0; nt < 2; ++nt) {
        accg[mt][nt] = __builtin_amdgcn_mfma_f32_16x16x32_bf16(af[mt], bgf[nt], accg[mt][nt], 0, 0, 0);
        accu[mt][nt] = __builtin_amdgcn_mfma_f32_16x16x32_bf16(af[mt], bud[nt], accu[mt][nt], 0, 0, 0);
      }
    __builtin_amdgcn_s_setprio(0);
    __builtin_amdgcn_sched_barrier(0);
    if (t + 1 < NT) WR(cur ^ 1);
    if (t + 2 < NT) LD((t + 2) * 32);
    asm volatile("s_waitcnt lgkmcnt(0)" ::: "memory");
    __builtin_amdgcn_sched_barrier(0);
    __builtin_amdgcn_s_barrier();
  }
#undef LD
#undef WR

#pragma unroll
  for (int mt = 0; mt < 4; ++mt)
#pragma unroll
    for (int nt = 0; nt < 2; ++nt)
#pragma unroll
      for (int r = 0; r < 4; ++r) {
        int row = row0 + wm + mt * 16 + q * 4 + r;
        int n = n0 + wn + nt * 16 + fm;
        float g = accg[mt][nt][r], u = accu[mt][nt][r];
        float hv = g / (1.f + __expf(-g)) * u;
        hsh[(size_t)row * ID + n] = f2bf(hv);
      }
}

// ---------------- down: shared MLP ------------------------------------------
template <int BF>
__global__ __launch_bounds__(256) void dn_shared_kernel(
    const unsigned short* __restrict__ hsh, const float* __restrict__ shd,
    const unsigned short* __restrict__ shdT, float* __restrict__ out) {
  const int row0 = blockIdx.y * 128;
  const int n0 = blockIdx.x * 64;
  const float* B = shd + n0;
  const unsigned short* T = shdT + (size_t)n0 * ID;

  __shared__ __align__(16) unsigned short As[2][128][40];
  __shared__ __align__(16) unsigned short Bs[2][64][36];

  const int tid = threadIdx.x;
  const int lane = tid & 63, wave = tid >> 6;
  const int wm = (wave >> 1) * 64, wn = (wave & 1) * 32;
  const int rA0 = tid >> 2, cA = (tid & 3) * 8, rA1 = rA0 + 64;
  const unsigned short* ap0 = hsh + (size_t)(row0 + rA0) * ID + cA;
  const unsigned short* ap1 = hsh + (size_t)(row0 + rA1) * ID + cA;
  const int nB = tid & 63;
  const int kq0 = tid >> 6;
  const int fm = lane & 15, q = lane >> 4;
  const int nrT = tid >> 2, kcT = (tid & 3) * 8;

  const f32x4 zf = {0.f, 0.f, 0.f, 0.f};
  f32x4 acc[4][2];
#pragma unroll
  for (int a = 0; a < 4; ++a)
#pragma unroll
    for (int b = 0; b < 2; ++b) acc[a][b] = zf;

  u32x4 ra0, ra1, tb;
  f32x4 rb0, rb1;

#define LD(K0)                                                                 \
  do {                                                                         \
    ra0 = *(const u32x4*)(const void*)(ap0 + (K0));                            \
    ra1 = *(const u32x4*)(const void*)(ap1 + (K0));                            \
    if constexpr (BF) {                                                        \
      tb = *(const u32x4*)(const void*)(T + (size_t)nrT * ID + (K0) + kcT);    \
    } else {                                                                   \
      const float* p = B + (size_t)((K0) + kq0 * 4) * HD + nB;                 \
      const float* pb = p + 16 * HD;                                           \
      rb0[0] = p[0]; rb0[1] = p[HD]; rb0[2] = p[2 * HD]; rb0[3] = p[3 * HD];   \
      rb1[0] = pb[0]; rb1[1] = pb[HD]; rb1[2] = pb[2 * HD]; rb1[3] = pb[3 * HD]; \
    }                                                                          \
  } while (0)

#define WR(BUF)                                                                \
  do {                                                                         \
    *(u32x4*)(void*)&As[BUF][rA0][cA] = ra0;                                   \
    *(u32x4*)(void*)&As[BUF][rA1][cA] = ra1;                                   \
    if constexpr (BF) {                                                        \
      u32x2 lo, hi;                                                            \
      lo[0] = tb[0]; lo[1] = tb[1]; hi[0] = tb[2]; hi[1] = tb[3];              \
      *(u32x2*)(void*)&Bs[BUF][nrT][kcT] = lo;                                 \
      *(u32x2*)(void*)&Bs[BUF][nrT][kcT + 4] = hi;                             \
    } else {                                                                   \
      u16x4 w;                                                                 \
      w[0] = f2bf(rb0[0]); w[1] = f2bf(rb0[1]); w[2] = f2bf(rb0[2]); w[3] = f2bf(rb0[3]); \
      *(u16x4*)(void*)&Bs[BUF][nB][kq0 * 4] = w;                               \
      w[0] = f2bf(rb1[0]); w[1] = f2bf(rb1[1]); w[2] = f2bf(rb1[2]); w[3] = f2bf(rb1[3]); \
      *(u16x4*)(void*)&Bs[BUF][nB][kq0 * 4 + 16] = w;                          \
    }                                                                          \
  } while (0)

  LD(0);
  WR(0);
  LD(32);
  asm volatile("s_waitcnt lgkmcnt(0)" ::: "memory");
  __builtin_amdgcn_sched_barrier(0);
  __builtin_amdgcn_s_barrier();

  constexpr int NT = ID / 32;
  for (int t = 0; t < NT; ++t) {
    const int cur = t & 1;
    bf16x8 af[4], bfr[2];
#pragma unroll
    for (int mt = 0; mt < 4; ++mt)
      af[mt] = __builtin_bit_cast(bf16x8,
               *(const u32x4*)(const void*)&As[cur][wm + mt * 16 + fm][q * 8]);
#pragma unroll
    for (int nt = 0; nt < 2; ++nt) {
      const unsigned short* bp = &Bs[cur][wn + nt * 16 + fm][q * 8];
      u32x2 lo = *(const u32x2*)(const void*)bp;
      u32x2 hi = *(const u32x2*)(const void*)(bp + 4);
      u32x4 v; v[0] = lo[0]; v[1] = lo[1]; v[2] = hi[0]; v[3] = hi[1];
      bfr[nt] = __builtin_bit_cast(bf16x8, v);
    }
    __builtin_amdgcn_s_setprio(1);
#pragma unroll
    for (int mt = 0; mt < 4; ++mt)
#pragma unroll
      for (int nt = 0; nt < 2; ++nt)
        acc[mt][nt] = __builtin_amdgcn_mfma_f32_16x16x32_bf16(af[mt], bfr[nt], acc[mt][nt], 0, 0, 0);
    __builtin_amdgcn_s_setprio(0);
    __builtin_amdgcn_sched_barrier(0);
    if (t + 1 < NT) WR(cur ^ 1);
    if (t + 2 < NT) LD((t + 2) * 32);
    asm volatile("s_waitcnt lgkmcnt(0)" ::: "memory");
    __builtin_amdgcn_sched_barrier(0);
    __builtin_amdgcn_s_barrier();
  }
#undef LD
#undef WR

#pragma unroll
  for (int mt = 0; mt < 4; ++mt)
#pragma unroll
    for (int nt = 0; nt < 2; ++nt)
#pragma unroll
      for (int r = 0; r < 4; ++r) {
        int row = row0 + wm + mt * 16 + q * 4 + r;
        int n = n0 + wn + nt * 16 + fm;
        out[(size_t)row * HD + n] = acc[mt][nt][r];
      }
}

// ---------------- down: routed experts (fused f32 B, += epilogue) ------------
__global__ __launch_bounds__(256) void dn_routed_kernel(
    const unsigned short* __restrict__ hrt, const float* __restrict__ dwn,
    const int* __restrict__ counts, const int* __restrict__ tlist,
    float* __restrict__ out) {
  const int e = blockIdx.z;
  const int cnt = counts[e];
  const int row0 = blockIdx.y * 128;
  if (row0 >= cnt) return;
  const int n0 = blockIdx.x * 64;
  const float* B = dwn + (size_t)e * ID * HD + n0;

  __shared__ int toks[128];
  __shared__ __align__(16) unsigned short As[2][128][40];
  __shared__ __align__(16) unsigned short Bs[2][64][36];

  const int tid = threadIdx.x;
  if (tid < 128) {
    int r = row0 + tid;
    toks[tid] = (r < cnt) ? tlist[e * TT + r] : -1;
  }
  __syncthreads();

  const int lane = tid & 63, wave = tid >> 6;
  const int wm = (wave >> 1) * 64, wn = (wave & 1) * 32;
  const int rA0 = tid >> 2, cA = (tid & 3) * 8, rA1 = rA0 + 64;
  const int tok0 = toks[rA0], tok1 = toks[rA1];
  const unsigned short* ap0 = hrt + ((tok0 >= 0) ? (size_t)tok0 * ID : 0) + cA;
  const unsigned short* ap1 = hrt + ((tok1 >= 0) ? (size_t)tok1 * ID : 0) + cA;
  const int nB = tid & 63;
  const int kq0 = tid >> 6;
  const int fm = lane & 15, q = lane >> 4;

  const f32x4 zf = {0.f, 0.f, 0.f, 0.f};
  const u32x4 z4 = {0u, 0u, 0u, 0u};
  f32x4 acc[4][2];
#pragma unroll
  for (int a = 0; a < 4; ++a)
#pragma unroll
    for (int b = 0; b < 2; ++b) acc[a][b] = zf;

  u32x4 ra0, ra1;
  f32x4 rb0, rb1;

#define LD(K0)                                                                 \
  do {                                                                         \
    ra0 = (tok0 >= 0) ? *(const u32x4*)(const void*)(ap0 + (K0)) : z4;         \
    ra1 = (tok1 >= 0) ? *(const u32x4*)(const void*)(ap1 + (K0)) : z4;         \
    const float* p = B + (size_t)((K0) + kq0 * 4) * HD + nB;                   \
    const float* pb = p + 16 * HD;                                             \
    rb0[0] = p[0]; rb0[1] = p[HD]; rb0[2] = p[2 * HD]; rb0[3] = p[3 * HD];     \
    rb1[0] = pb[0]; rb1[1] = pb[HD]; rb1[2] = pb[2 * HD]; rb1[3] = pb[3 * HD]; \
  } while (0)

#define WR(BUF)                                                                \
  do {                                                                         \
    *(u32x4*)(void*)&As[BUF][rA0][cA] = ra0;                                   \
    *(u32x4*)(void*)&As[BUF][rA1][cA] = ra1;                                   \
    u16x4 w;                                                                   \
    w[0] = f2bf(rb0[0]); w[1] = f2bf(rb0[1]); w[2] = f2bf(rb0[2]); w[3] = f2bf(rb0[3]); \
    *(u16x4*)(void*)&Bs[BUF][nB][kq0 * 4] = w;                                 \
    w[0] = f2bf(rb1[0]); w[1] = f2bf(rb1[1]); w[2] = f2bf(rb1[2]); w[3] = f2bf(rb1[3]); \
    *(u16x4*)(void*)&Bs[BUF][nB][kq0 * 4 + 16] = w;                            \
  } while (0)

  LD(0);
  WR(0);
  LD(32);
  asm volatile("s_waitcnt lgkmcnt(0)" ::: "memory");
  __builtin_amdgcn_sched_barrier(0);
  __builtin_amdgcn_s_barrier();

  constexpr int NT = ID / 32;
  for (int t = 0; t < NT; ++t) {
    const int cur = t & 1;
    bf16x8 af[4], bfr[2];
#pragma unroll
    for (int mt = 0; mt < 4; ++mt)
      af[mt] = __builtin_bit_cast(bf16x8,
               *(const u32x4*)(const void*)&As[cur][wm + mt * 16 + fm][q * 8]);
#pragma unroll
    for (int nt = 0; nt < 2; ++nt) {
      const unsigned short* bp = &Bs[cur][wn + nt * 16 + fm][q * 8];
      u32x2 lo = *(const u32x2*)(const void*)bp;
      u32x2 hi = *(const u32x2*)(const void*)(bp + 4);
      u32x4 v; v[0] = lo[0]; v[1] = lo[1]; v[2] = hi[0]; v[3] = hi[1];
      bfr[nt] = __builtin_bit_cast(bf16x8, v);
    }
    __builtin_amdgcn_s_setprio(1);
#pragma unroll
    for (int mt = 0; mt < 4; ++mt)
#pragma unroll
      for (int nt = 0; nt < 2; ++nt)
        acc[mt][nt] = __builtin_amdgcn_mfma_f32_16x16x32_bf16(af[mt], bfr[nt], acc[mt][nt], 0, 0, 0);
    __builtin_amdgcn_s_setprio(0);
    __builtin_amdgcn_sched_barrier(0);
    if (t + 1 < NT) WR(cur ^ 1);
    if (t + 2 < NT) LD((t + 2) * 32);
    asm volatile("s_waitcnt lgkmcnt(0)" ::: "memory");
    __builtin_amdgcn_sched_barrier(0);
    __builtin_amdgcn_s_barrier();
  }
#undef LD
#undef WR

#pragma unroll
  for (int mt = 0; mt < 4; ++mt)
#pragma unroll
    for (int nt = 0; nt < 2; ++nt)
#pragma unroll
      for (int r = 0; r < 4; ++r) {
        int ml = wm + mt * 16 + q * 4 + r;
        if (row0 + ml < cnt) {
          int tok = toks[ml];
          int n = n0 + wn + nt * 16 + fm;
          out[(size_t)tok * HD + n] += acc[mt][nt][r];
        }
      }
}

extern "C" void kernel_launch(void* const* d_in, const int* in_sizes, int n_in,
                              void* d_out, int out_size, void* d_ws, size_t ws_size,
                              hipStream_t stream) {
  const float* x   = (const float*)d_in[0];
  const float* rw  = (const float*)d_in[1];
  const float* gup = (const float*)d_in[2];
  const float* dwn = (const float*)d_in[3];
  const float* shg = (const float*)d_in[4];
  const float* shu = (const float*)d_in[5];
  const float* shd = (const float*)d_in[6];
  float* out = (float*)d_out;

  char* ws = (char*)d_ws;
  int* counts = (int*)ws;                                    // 32 B
  int* tlist = (int*)(ws + 1024);                            // 64 KB
  unsigned short* xb  = (unsigned short*)(ws + (1 << 17));               // 8 MB
  unsigned short* xsb = (unsigned short*)(ws + (1 << 17) + 8388608);     // 8 MB
  unsigned short* hsh = (unsigned short*)(ws + (1 << 17) + 16777216);    // 16 MB
  unsigned short* hrt = (unsigned short*)(ws + (1 << 17) + 33554432);    // 16 MB
  const size_t WB = (size_t)(1 << 17) + 50331648;
  unsigned short* shgT = (unsigned short*)(ws + WB);                     // 16 MB
  unsigned short* shuT = (unsigned short*)(ws + WB + 16777216);          // 16 MB
  unsigned short* shdT = (unsigned short*)(ws + WB + 33554432);          // 16 MB
  const size_t need = WB + 3ull * 16777216ull;
  const int shbf = (ws_size >= need) ? 1 : 0;

  hipLaunchKernelGGL(init_kernel, dim3(1), dim3(64), 0, stream, counts);
  hipLaunchKernelGGL(router_kernel, dim3(TT), dim3(256), 0, stream,
                     x, rw, out + (size_t)TT * HD, xb, xsb, counts, tlist);
  if (shbf)
    hipLaunchKernelGGL(tconv_kernel, dim3(64, 64, 3), dim3(256), 0, stream,
                       shg, shu, shd, shgT, shuT, shdT);
  hipLaunchKernelGGL(gu_routed_kernel, dim3(ID / 64, TT / 128, NE), dim3(256), 0, stream,
                     xsb, gup, counts, tlist, hrt);
  if (shbf)
    hipLaunchKernelGGL((gu_shared_kernel<1>), dim3(ID / 64, TT / 128), dim3(256), 0, stream,
                       xb, shg, shu, shgT, shuT, hsh);
  else
    hipLaunchKernelGGL((gu_shared_kernel<0>), dim3(ID / 64, TT / 128), dim3(256), 0, stream,
                       xb, shg, shu, shgT, shuT, hsh);
  if (shbf)
    hipLaunchKernelGGL((dn_shared_kernel<1>), dim3(HD / 64, TT / 128), dim3(256), 0, stream,
                       hsh, shd, shdT, out);
  else
    hipLaunchKernelGGL((dn_shared_kernel<0>), dim3(HD / 64, TT / 128), dim3(256), 0, stream,
                       hsh, shd, shdT, out);
  hipLaunchKernelGGL(dn_routed_kernel, dim3(HD / 64, TT / 128, NE), dim3(256), 0, stream,
                     hrt, dwn, counts, tlist, out);
}